// Round 17
// baseline (147.602 us; speedup 1.0000x reference)
//
#include <hip/hip_runtime.h>
#include <cstdint>

#define BB 16
#define MM 128
#define TT 12000
constexpr int BT = BB * TT; // 192000

// K1: per-column stats over the M axis, sequential in m (reference order).
// anti-fma via `#pragma clang fp contract(off)` (proven round 13).
__global__ void k1_colstats(const float* __restrict__ mel,
                            float* __restrict__ ssq,
                            float* __restrict__ dotv,
                            float* __restrict__ cmean,
                            unsigned int* __restrict__ counts) {
    if (blockIdx.x == 0 && blockIdx.y == 0 && threadIdx.x < 8)
        counts[threadIdx.x] = 0u;
    const int b = blockIdx.y;
    const int t = blockIdx.x * blockDim.x + threadIdx.x;
    if (t >= TT) return;
    const float* base = mel + (size_t)b * MM * TT;
    float accd = 0.f, accq = 0.f, accs = 0.f;
    {
#pragma clang fp contract(off)
        for (int m = 0; m < MM; ++m) {
            const float* rowp = base + (size_t)m * TT;
            float cur = rowp[t];
            float prev = (t > 0) ? rowp[t - 1] : 0.f;
            accd += prev * cur;
            accq += cur * cur;
            accs += cur;
        }
    }
    size_t i = (size_t)b * TT + t;
    ssq[i] = accq; dotv[i] = accd; cmean[i] = accs * (1.0f / MM);
}

// kA: temporal = 1 - std(smooth, ddof=1). Row staged to LDS once.
__global__ void kA_temporal(const float* __restrict__ cmean,
                            float* __restrict__ temporal) {
    const int b = blockIdx.x;
    const int tid = threadIdx.x;
    __shared__ __align__(16) float row_s[TT];
    __shared__ float red[256];
    __shared__ float mean_s;
    const float4* c4 = (const float4*)(cmean + (size_t)b * TT);
    float4* r4 = (float4*)row_s;
    for (int i = tid; i < TT / 4; i += 256) r4[i] = c4[i];
    __syncthreads();

    float s = 0.f;
    for (int t = tid; t < TT; t += 256) {
        float v = 0.f;
        int lo = t - 2 < 0 ? 0 : t - 2;
        int hi = t + 2 >= TT ? TT - 1 : t + 2;
        for (int j = lo; j <= hi; ++j) v += row_s[j];
        s += v / 5.0f;
    }
    red[tid] = s; __syncthreads();
    for (int o = 128; o > 0; o >>= 1) {
        if (tid < o) red[tid] += red[tid + o];
        __syncthreads();
    }
    if (tid == 0) mean_s = red[0] / (float)TT;
    __syncthreads();
    float mean = mean_s;
    float ss = 0.f;
    for (int t = tid; t < TT; t += 256) {
        float v = 0.f;
        int lo = t - 2 < 0 ? 0 : t - 2;
        int hi = t + 2 >= TT ? TT - 1 : t + 2;
        for (int j = lo; j <= hi; ++j) v += row_s[j];
        float sm = v / 5.0f - mean;
        ss += sm * sm;
    }
    red[tid] = ss; __syncthreads();
    for (int o = 128; o > 0; o >>= 1) {
        if (tid < o) red[tid] += red[tid + o];
        __syncthreads();
    }
    if (tid == 0) {
        float var = red[0] / (float)(TT - 1);
        temporal[b] = 1.0f - sqrtf(var);
    }
}

// kB: cons — bitwise replica of the passing version, 750 blocks.
__global__ void kB_cons(const float* __restrict__ ssq,
                        const float* __restrict__ dotv,
                        const float* __restrict__ spec,
                        const float* __restrict__ temporal,
                        const float* __restrict__ wraw,
                        float* __restrict__ cons) {
    const int idx = blockIdx.x * 256 + threadIdx.x;
    const int b = idx / TT;
    const int t = idx - b * TT;
    float x0 = wraw[0], x1 = wraw[1], x2 = wraw[2];
    float mx = fmaxf(x0, fmaxf(x1, x2));
    float e0 = expf(x0 - mx), e1 = expf(x1 - mx), e2 = expf(x2 - mx);
    float es = (e0 + e1) + e2;
    float w0 = e0 / es, w1 = e1 / es, w2 = e2 / es;
    float mel_sim, spec_sim;
    if (t == 0) { mel_sim = 0.f; spec_sim = 1.f; }
    else {
        float na = fmaxf(sqrtf(ssq[idx - 1]), 1e-8f);
        float nb = fmaxf(sqrtf(ssq[idx]),     1e-8f);
        float den = na * nb; asm volatile("" : "+v"(den));
        mel_sim = dotv[idx] / den;
        float d = fabsf(spec[idx] - spec[idx - 1]);
        spec_sim = 1.0f / (1.0f + d);
    }
    float pa = w0 * mel_sim;     asm volatile("" : "+v"(pa));
    float pb = w1 * spec_sim;    asm volatile("" : "+v"(pb));
    float pc = w2 * temporal[b]; asm volatile("" : "+v"(pc));
    cons[idx] = (pa + pb) + pc;
}

// Four dependent adds; carry enters via register P and leaves in R3.
// Bitwise the reference sequential-cumsum order.
#define ADD4(P, R0, R1, R2, R3) \
    "v_add_f32 v" R0 ", v" P  ", v" R0 "\n\t" \
    "v_add_f32 v" R1 ", v" R0 ", v" R1 "\n\t" \
    "v_add_f32 v" R2 ", v" R1 ", v" R2 "\n\t" \
    "v_add_f32 v" R3 ", v" R2 ", v" R3 "\n\t"

// One sub-batch (16 elems, all 16 lanes/rows in lockstep): ONE counted
// vmcnt wait (40 = 48 outstanding - 8 oldest = this SB's operand loads,
// FIFO-exact with a 24-quad/6-SB ring), 16 chained adds (carry through
// quad R3s, one mov at SB end — round-9-proven), 4 CS stores, 4 prefetch
// loads 6 SBs (384 B) ahead. v40 = per-lane byte offset, v43 = carry.
#define SCB(Q0a,Q0b,Q0c,Q0d, Q1a,Q1b,Q1c,Q1d, Q2a,Q2b,Q2c,Q2d, Q3a,Q3b,Q3c,Q3d, O0,O1,O2,O3, P0,P1,P2,P3) \
    "s_waitcnt vmcnt(40)\n\t" \
    ADD4("43", Q0a, Q0b, Q0c, Q0d) \
    ADD4(Q0d,  Q1a, Q1b, Q1c, Q1d) \
    ADD4(Q1d,  Q2a, Q2b, Q2c, Q2d) \
    ADD4(Q2d,  Q3a, Q3b, Q3c, Q3d) \
    "v_mov_b32 v43, v" Q3d "\n\t" \
    "global_store_dwordx4 v40, v[" Q0a ":" Q0d "], %1 offset:" O0 "\n\t" \
    "global_store_dwordx4 v40, v[" Q1a ":" Q1d "], %1 offset:" O1 "\n\t" \
    "global_store_dwordx4 v40, v[" Q2a ":" Q2d "], %1 offset:" O2 "\n\t" \
    "global_store_dwordx4 v40, v[" Q3a ":" Q3d "], %1 offset:" O3 "\n\t" \
    "global_load_dwordx4 v[" Q0a ":" Q0d "], v40, %0 offset:" P0 "\n\t" \
    "global_load_dwordx4 v[" Q1a ":" Q1d "], v40, %0 offset:" P1 "\n\t" \
    "global_load_dwordx4 v[" Q2a ":" Q2d "], v40, %0 offset:" P2 "\n\t" \
    "global_load_dwordx4 v[" Q3a ":" Q3d "], v40, %0 offset:" P3 "\n\t"

// kC: 16-lane SIMT scan in asm — lane r runs row r's exact sequential f32
// cumsum; 24-quad ring (v48..v143), one wait per 16 elems.
__global__ void __launch_bounds__(64)
kC_scan16(const float* __restrict__ cons,
          float* __restrict__ CSg) {
    const int r = threadIdx.x;
    if (r >= BB) return;
    uint32_t voff = (uint32_t)(r * TT * 4);   // per-lane row base (bytes)
    asm volatile(
        "v_mov_b32 v40, %2\n\t"
        "v_mov_b32 v43, 0\n\t"
        // prologue: fill 24-quad ring (groups 0..23)
        "global_load_dwordx4 v[48:51],   v40, %0 offset:0\n\t"
        "global_load_dwordx4 v[52:55],   v40, %0 offset:16\n\t"
        "global_load_dwordx4 v[56:59],   v40, %0 offset:32\n\t"
        "global_load_dwordx4 v[60:63],   v40, %0 offset:48\n\t"
        "global_load_dwordx4 v[64:67],   v40, %0 offset:64\n\t"
        "global_load_dwordx4 v[68:71],   v40, %0 offset:80\n\t"
        "global_load_dwordx4 v[72:75],   v40, %0 offset:96\n\t"
        "global_load_dwordx4 v[76:79],   v40, %0 offset:112\n\t"
        "global_load_dwordx4 v[80:83],   v40, %0 offset:128\n\t"
        "global_load_dwordx4 v[84:87],   v40, %0 offset:144\n\t"
        "global_load_dwordx4 v[88:91],   v40, %0 offset:160\n\t"
        "global_load_dwordx4 v[92:95],   v40, %0 offset:176\n\t"
        "global_load_dwordx4 v[96:99],   v40, %0 offset:192\n\t"
        "global_load_dwordx4 v[100:103], v40, %0 offset:208\n\t"
        "global_load_dwordx4 v[104:107], v40, %0 offset:224\n\t"
        "global_load_dwordx4 v[108:111], v40, %0 offset:240\n\t"
        "global_load_dwordx4 v[112:115], v40, %0 offset:256\n\t"
        "global_load_dwordx4 v[116:119], v40, %0 offset:272\n\t"
        "global_load_dwordx4 v[120:123], v40, %0 offset:288\n\t"
        "global_load_dwordx4 v[124:127], v40, %0 offset:304\n\t"
        "global_load_dwordx4 v[128:131], v40, %0 offset:320\n\t"
        "global_load_dwordx4 v[132:135], v40, %0 offset:336\n\t"
        "global_load_dwordx4 v[136:139], v40, %0 offset:352\n\t"
        "global_load_dwordx4 v[140:143], v40, %0 offset:368\n\t"
        "s_waitcnt vmcnt(0)\n\t"
        "s_mov_b32 s20, 125\n\t"           // 125 passes x 24 groups = 3000
        "3:\n\t"
        SCB("48","49","50","51",  "52","53","54","55",
            "56","57","58","59",  "60","61","62","63",
            "0","16","32","48",   "384","400","416","432")
        SCB("64","65","66","67",  "68","69","70","71",
            "72","73","74","75",  "76","77","78","79",
            "64","80","96","112", "448","464","480","496")
        SCB("80","81","82","83",  "84","85","86","87",
            "88","89","90","91",  "92","93","94","95",
            "128","144","160","176", "512","528","544","560")
        SCB("96","97","98","99",  "100","101","102","103",
            "104","105","106","107", "108","109","110","111",
            "192","208","224","240", "576","592","608","624")
        SCB("112","113","114","115", "116","117","118","119",
            "120","121","122","123", "124","125","126","127",
            "256","272","288","304", "640","656","672","688")
        SCB("128","129","130","131", "132","133","134","135",
            "136","137","138","139", "140","141","142","143",
            "320","336","352","368", "704","720","736","752")
        "v_add_u32 v40, 384, v40\n\t"
        "s_sub_u32 s20, s20, 1\n\t"
        "s_cmp_lg_u32 s20, 0\n\t"
        "s_cbranch_scc1 3b\n\t"
        "s_waitcnt vmcnt(0)\n\t"
        :
        : "s"(cons), "s"(CSg), "v"(voff)
        : "v40", "v43",
          "v48", "v49", "v50", "v51", "v52", "v53", "v54", "v55",
          "v56", "v57", "v58", "v59", "v60", "v61", "v62", "v63",
          "v64", "v65", "v66", "v67", "v68", "v69", "v70", "v71",
          "v72", "v73", "v74", "v75", "v76", "v77", "v78", "v79",
          "v80", "v81", "v82", "v83", "v84", "v85", "v86", "v87",
          "v88", "v89", "v90", "v91", "v92", "v93", "v94", "v95",
          "v96", "v97", "v98", "v99", "v100", "v101", "v102", "v103",
          "v104", "v105", "v106", "v107", "v108", "v109", "v110", "v111",
          "v112", "v113", "v114", "v115", "v116", "v117", "v118", "v119",
          "v120", "v121", "v122", "v123", "v124", "v125", "v126", "v127",
          "v128", "v129", "v130", "v131", "v132", "v133", "v134", "v135",
          "v136", "v137", "v138", "v139", "v140", "v141", "v142", "v143",
          "s20", "scc", "memory");
}

// kD: candbits + local/step + 5-iter never-done sim. Per-iteration
// "any nonzero adjustment" exported as a FLAG (plain store of 1).
__global__ void kD_prepare(const float* __restrict__ cons,
                           const float* __restrict__ CSg,
                           const float* __restrict__ init,
                           float* __restrict__ stepv,
                           float* __restrict__ candf,
                           unsigned int* __restrict__ counts) {
    const int idx = blockIdx.x * 256 + threadIdx.x;
    const int b = idx / TT;
    const int t = idx - b * TT;
    __shared__ unsigned sflag[5];
    if (threadIdx.x < 5) sflag[threadIdx.x] = 0u;
    __syncthreads();

    const float* csr = CSg + (size_t)b * TT;   // inclusive cumsum
    int lo = t - 2; if (lo < 0) lo = 0;
    int hi = t + 3; if (hi > TT) hi = TT;
    float csH = csr[hi - 1];                   // == padded CS[hi]
    float csL = (lo > 0) ? csr[lo - 1] : 0.f;  // == padded CS[lo]
    float local = (csH - csL) / (float)(hi - lo);
    float dir = (local > 0.7f) ? -0.1f : ((local < 0.4f) ? 0.1f : 0.0f);
    bool interior = (t >= 1) && (t <= TT - 2);
    float step = interior ? dir : 0.0f;
    float g = (t == 0) ? 0.f : fabsf(cons[idx] - cons[idx - 1]);
    float cand = (g > 0.15f) ? 1.f : 0.f;
    float r = init[idx];
    bool nz[5];
#pragma unroll
    for (int j = 0; j < 5; ++j) {
        float adj = (fmaxf(cand, r) > 0.5f) ? step : 0.0f;
        nz[j] = (adj != 0.0f);
        r = fminf(fmaxf(r + adj, 0.0f), 1.0f);
    }
    stepv[idx] = step; candf[idx] = cand;
    const int lane = threadIdx.x & 63;
#pragma unroll
    for (int j = 0; j < 5; ++j) {
        unsigned long long mb = __ballot(nz[j]);
        if (lane == 0 && mb) atomicOr(&sflag[j], 1u);   // LDS-scope, cheap
    }
    __syncthreads();
    if (threadIdx.x < 5 && sflag[threadIdx.x]) counts[threadIdx.x] = 1u;
}

// K_final: freeze at the first iteration whose adjustment flag is 0.
__global__ void k_final(const float* __restrict__ init,
                        const float* __restrict__ stepv,
                        const float* __restrict__ candf,
                        const unsigned int* __restrict__ counts,
                        float* __restrict__ outp) {
    const int idx = blockIdx.x * 256 + threadIdx.x;
    float r = init[idx];
    float step = stepv[idx];
    float cand = candf[idx];
    unsigned c[5];
#pragma unroll
    for (int j = 0; j < 5; ++j) c[j] = counts[j];
#pragma unroll
    for (int j = 0; j < 5; ++j) {
        if (c[j] == 0u) break;
        float adj = (fmaxf(cand, r) > 0.5f) ? step : 0.0f;
        r = fminf(fmaxf(r + adj, 0.0f), 1.0f);
    }
    outp[idx] = r;
}

extern "C" void kernel_launch(void* const* d_in, const int* in_sizes, int n_in,
                              void* d_out, int out_size, void* d_ws, size_t ws_size,
                              hipStream_t stream) {
    const float* mel  = (const float*)d_in[0];
    const float* spec = (const float*)d_in[1];
    const float* init = (const float*)d_in[2];
    const float* wts  = (const float*)d_in[3];

    float* ws = (float*)d_ws;
    float* ssq   = ws;                 // 192000
    float* dotv  = ws + 192000;        // 192000
    float* cmean = ws + 384000;        // 192000
    float* cons  = ws + 576000;        // 192000
    float* CSg   = ws + 768000;        // 192000 (also absorbs tail prefetch)
    float* stepv = ws + 960000;        // 192000
    float* candf = ws + 1152000;       // 192000
    float* temporal = ws + 1344000;    // 16
    unsigned int* counts = (unsigned int*)(ws + 1344016); // 8 u32

    dim3 g1((TT + 255) / 256, BB);
    k1_colstats<<<g1, 256, 0, stream>>>(mel, ssq, dotv, cmean, counts);
    kA_temporal<<<BB, 256, 0, stream>>>(cmean, temporal);
    kB_cons<<<BT / 256, 256, 0, stream>>>(ssq, dotv, spec, temporal, wts, cons);
    kC_scan16<<<1, 64, 0, stream>>>(cons, CSg);
    kD_prepare<<<BT / 256, 256, 0, stream>>>(cons, CSg, init, stepv, candf, counts);
    k_final<<<BT / 256, 256, 0, stream>>>(init, stepv, candf, counts, (float*)d_out);
}

// Round 18
// 122.800 us; speedup vs baseline: 1.2020x; 1.2020x over previous
//
#include <hip/hip_runtime.h>
#include <cstdint>

#define BB 16
#define MM 128
#define TT 12000
constexpr int BT = BB * TT; // 192000

// Q4-interleaved scan layout: element (row b, pos t), t=4g+j lives at
// q[(g*16 + b)*4 + j]  (one float4 per (group, row); 16 rows contiguous
// per group -> a 16-lane quad access covers 256 contiguous bytes).

// K1: per-column stats over the M axis, sequential in m (reference order).
// anti-fma via `#pragma clang fp contract(off)` (proven round 13).
__global__ void k1_colstats(const float* __restrict__ mel,
                            float* __restrict__ ssq,
                            float* __restrict__ dotv,
                            float* __restrict__ cmean,
                            unsigned int* __restrict__ counts) {
    if (blockIdx.x == 0 && blockIdx.y == 0 && threadIdx.x < 8)
        counts[threadIdx.x] = 0u;
    const int b = blockIdx.y;
    const int t = blockIdx.x * blockDim.x + threadIdx.x;
    if (t >= TT) return;
    const float* base = mel + (size_t)b * MM * TT;
    float accd = 0.f, accq = 0.f, accs = 0.f;
    {
#pragma clang fp contract(off)
        for (int m = 0; m < MM; ++m) {
            const float* rowp = base + (size_t)m * TT;
            float cur = rowp[t];
            float prev = (t > 0) ? rowp[t - 1] : 0.f;
            accd += prev * cur;
            accq += cur * cur;
            accs += cur;
        }
    }
    size_t i = (size_t)b * TT + t;
    ssq[i] = accq; dotv[i] = accd; cmean[i] = accs * (1.0f / MM);
}

// kA: temporal = 1 - std(smooth, ddof=1). Row staged to LDS once.
__global__ void kA_temporal(const float* __restrict__ cmean,
                            float* __restrict__ temporal) {
    const int b = blockIdx.x;
    const int tid = threadIdx.x;
    __shared__ __align__(16) float row_s[TT];
    __shared__ float red[256];
    __shared__ float mean_s;
    const float4* c4 = (const float4*)(cmean + (size_t)b * TT);
    float4* r4 = (float4*)row_s;
    for (int i = tid; i < TT / 4; i += 256) r4[i] = c4[i];
    __syncthreads();

    float s = 0.f;
    for (int t = tid; t < TT; t += 256) {
        float v = 0.f;
        int lo = t - 2 < 0 ? 0 : t - 2;
        int hi = t + 2 >= TT ? TT - 1 : t + 2;
        for (int j = lo; j <= hi; ++j) v += row_s[j];
        s += v / 5.0f;
    }
    red[tid] = s; __syncthreads();
    for (int o = 128; o > 0; o >>= 1) {
        if (tid < o) red[tid] += red[tid + o];
        __syncthreads();
    }
    if (tid == 0) mean_s = red[0] / (float)TT;
    __syncthreads();
    float mean = mean_s;
    float ss = 0.f;
    for (int t = tid; t < TT; t += 256) {
        float v = 0.f;
        int lo = t - 2 < 0 ? 0 : t - 2;
        int hi = t + 2 >= TT ? TT - 1 : t + 2;
        for (int j = lo; j <= hi; ++j) v += row_s[j];
        float sm = v / 5.0f - mean;
        ss += sm * sm;
    }
    red[tid] = ss; __syncthreads();
    for (int o = 128; o > 0; o >>= 1) {
        if (tid < o) red[tid] += red[tid + o];
        __syncthreads();
    }
    if (tid == 0) {
        float var = red[0] / (float)(TT - 1);
        temporal[b] = 1.0f - sqrtf(var);
    }
}

// kB: cons — same arithmetic as the passing version; additionally writes
// the Q4-interleaved copy for the scan (same value, extra store only).
__global__ void kB_cons(const float* __restrict__ ssq,
                        const float* __restrict__ dotv,
                        const float* __restrict__ spec,
                        const float* __restrict__ temporal,
                        const float* __restrict__ wraw,
                        float* __restrict__ cons,
                        float* __restrict__ consq) {
    const int idx = blockIdx.x * 256 + threadIdx.x;
    const int b = idx / TT;
    const int t = idx - b * TT;
    float x0 = wraw[0], x1 = wraw[1], x2 = wraw[2];
    float mx = fmaxf(x0, fmaxf(x1, x2));
    float e0 = expf(x0 - mx), e1 = expf(x1 - mx), e2 = expf(x2 - mx);
    float es = (e0 + e1) + e2;
    float w0 = e0 / es, w1 = e1 / es, w2 = e2 / es;
    float mel_sim, spec_sim;
    if (t == 0) { mel_sim = 0.f; spec_sim = 1.f; }
    else {
        float na = fmaxf(sqrtf(ssq[idx - 1]), 1e-8f);
        float nb = fmaxf(sqrtf(ssq[idx]),     1e-8f);
        float den = na * nb; asm volatile("" : "+v"(den));
        mel_sim = dotv[idx] / den;
        float d = fabsf(spec[idx] - spec[idx - 1]);
        spec_sim = 1.0f / (1.0f + d);
    }
    float pa = w0 * mel_sim;     asm volatile("" : "+v"(pa));
    float pb = w1 * spec_sim;    asm volatile("" : "+v"(pb));
    float pc = w2 * temporal[b]; asm volatile("" : "+v"(pc));
    float c = (pa + pb) + pc;
    cons[idx] = c;
    consq[((t >> 2) * 16 + b) * 4 + (t & 3)] = c;
}

// Four dependent adds; carry enters via register P and leaves in R3.
// Bitwise the reference sequential-cumsum order.
#define ADD4(P, R0, R1, R2, R3) \
    "v_add_f32 v" R0 ", v" P  ", v" R0 "\n\t" \
    "v_add_f32 v" R1 ", v" R0 ", v" R1 "\n\t" \
    "v_add_f32 v" R2 ", v" R1 ", v" R2 "\n\t" \
    "v_add_f32 v" R3 ", v" R2 ", v" R3 "\n\t"

// One sub-batch (4 groups = 16 elems, Q4 layout): ONE vmcnt wait
// (40 = 5 younger SBs x 8 ops, FIFO-exact with the 6-SB ring), 16 chained
// adds, carry snapshot, 4 contiguous-256B stores (CS_q via v40), 4
// prefetch loads 6 SBs ahead (cons_q via v42 = v40+6144), pointer bumps.
#define SCQ(Q0a,Q0b,Q0c,Q0d, Q1a,Q1b,Q1c,Q1d, Q2a,Q2b,Q2c,Q2d, Q3a,Q3b,Q3c,Q3d) \
    "s_waitcnt vmcnt(40)\n\t" \
    ADD4("43", Q0a, Q0b, Q0c, Q0d) \
    ADD4(Q0d,  Q1a, Q1b, Q1c, Q1d) \
    ADD4(Q1d,  Q2a, Q2b, Q2c, Q2d) \
    ADD4(Q2d,  Q3a, Q3b, Q3c, Q3d) \
    "v_mov_b32 v43, v" Q3d "\n\t" \
    "global_store_dwordx4 v40, v[" Q0a ":" Q0d "], %1 offset:0\n\t" \
    "global_store_dwordx4 v40, v[" Q1a ":" Q1d "], %1 offset:256\n\t" \
    "global_store_dwordx4 v40, v[" Q2a ":" Q2d "], %1 offset:512\n\t" \
    "global_store_dwordx4 v40, v[" Q3a ":" Q3d "], %1 offset:768\n\t" \
    "global_load_dwordx4 v[" Q0a ":" Q0d "], v42, %0 offset:0\n\t" \
    "global_load_dwordx4 v[" Q1a ":" Q1d "], v42, %0 offset:256\n\t" \
    "global_load_dwordx4 v[" Q2a ":" Q2d "], v42, %0 offset:512\n\t" \
    "global_load_dwordx4 v[" Q3a ":" Q3d "], v42, %0 offset:768\n\t" \
    "v_add_u32 v40, 0x400, v40\n\t" \
    "v_add_u32 v42, 0x400, v42\n\t"

// kC: 16-lane SIMT scan in asm on the Q4-interleaved layout — every
// quad access is 256 contiguous bytes (4 lines) instead of 16 scattered
// lines (the round-15..17 ~85us wall). 24-quad ring, wait per 16 elems.
__global__ void __launch_bounds__(64)
kC_scan16(const float* __restrict__ consq,
          float* __restrict__ CSq) {
    const int r = threadIdx.x;
    if (r >= BB) return;
    uint32_t voff = (uint32_t)(r * 16);   // per-lane byte offset in a group
    asm volatile(
        "v_mov_b32 v40, %2\n\t"
        "v_mov_b32 v43, 0\n\t"
        // prologue: fill 24-quad ring (groups 0..23)
        "global_load_dwordx4 v[48:51],   v40, %0 offset:0\n\t"
        "global_load_dwordx4 v[52:55],   v40, %0 offset:256\n\t"
        "global_load_dwordx4 v[56:59],   v40, %0 offset:512\n\t"
        "global_load_dwordx4 v[60:63],   v40, %0 offset:768\n\t"
        "global_load_dwordx4 v[64:67],   v40, %0 offset:1024\n\t"
        "global_load_dwordx4 v[68:71],   v40, %0 offset:1280\n\t"
        "global_load_dwordx4 v[72:75],   v40, %0 offset:1536\n\t"
        "global_load_dwordx4 v[76:79],   v40, %0 offset:1792\n\t"
        "global_load_dwordx4 v[80:83],   v40, %0 offset:2048\n\t"
        "global_load_dwordx4 v[84:87],   v40, %0 offset:2304\n\t"
        "global_load_dwordx4 v[88:91],   v40, %0 offset:2560\n\t"
        "global_load_dwordx4 v[92:95],   v40, %0 offset:2816\n\t"
        "global_load_dwordx4 v[96:99],   v40, %0 offset:3072\n\t"
        "global_load_dwordx4 v[100:103], v40, %0 offset:3328\n\t"
        "global_load_dwordx4 v[104:107], v40, %0 offset:3584\n\t"
        "global_load_dwordx4 v[108:111], v40, %0 offset:3840\n\t"
        "v_add_u32 v41, 0x1000, v40\n\t"
        "global_load_dwordx4 v[112:115], v41, %0 offset:0\n\t"
        "global_load_dwordx4 v[116:119], v41, %0 offset:256\n\t"
        "global_load_dwordx4 v[120:123], v41, %0 offset:512\n\t"
        "global_load_dwordx4 v[124:127], v41, %0 offset:768\n\t"
        "global_load_dwordx4 v[128:131], v41, %0 offset:1024\n\t"
        "global_load_dwordx4 v[132:135], v41, %0 offset:1280\n\t"
        "global_load_dwordx4 v[136:139], v41, %0 offset:1536\n\t"
        "global_load_dwordx4 v[140:143], v41, %0 offset:1792\n\t"
        "v_add_u32 v42, 0x1800, v40\n\t"   // load base: 24 groups ahead
        "s_waitcnt vmcnt(0)\n\t"
        "s_mov_b32 s20, 125\n\t"           // 125 passes x 6 SBs x 4 groups = 3000
        "3:\n\t"
        SCQ("48","49","50","51",  "52","53","54","55",
            "56","57","58","59",  "60","61","62","63")
        SCQ("64","65","66","67",  "68","69","70","71",
            "72","73","74","75",  "76","77","78","79")
        SCQ("80","81","82","83",  "84","85","86","87",
            "88","89","90","91",  "92","93","94","95")
        SCQ("96","97","98","99",  "100","101","102","103",
            "104","105","106","107", "108","109","110","111")
        SCQ("112","113","114","115", "116","117","118","119",
            "120","121","122","123", "124","125","126","127")
        SCQ("128","129","130","131", "132","133","134","135",
            "136","137","138","139", "140","141","142","143")
        "s_sub_u32 s20, s20, 1\n\t"
        "s_cmp_lg_u32 s20, 0\n\t"
        "s_cbranch_scc1 3b\n\t"
        "s_waitcnt vmcnt(0)\n\t"
        :
        : "s"(consq), "s"(CSq), "v"(voff)
        : "v40", "v41", "v42", "v43",
          "v48", "v49", "v50", "v51", "v52", "v53", "v54", "v55",
          "v56", "v57", "v58", "v59", "v60", "v61", "v62", "v63",
          "v64", "v65", "v66", "v67", "v68", "v69", "v70", "v71",
          "v72", "v73", "v74", "v75", "v76", "v77", "v78", "v79",
          "v80", "v81", "v82", "v83", "v84", "v85", "v86", "v87",
          "v88", "v89", "v90", "v91", "v92", "v93", "v94", "v95",
          "v96", "v97", "v98", "v99", "v100", "v101", "v102", "v103",
          "v104", "v105", "v106", "v107", "v108", "v109", "v110", "v111",
          "v112", "v113", "v114", "v115", "v116", "v117", "v118", "v119",
          "v120", "v121", "v122", "v123", "v124", "v125", "v126", "v127",
          "v128", "v129", "v130", "v131", "v132", "v133", "v134", "v135",
          "v136", "v137", "v138", "v139", "v140", "v141", "v142", "v143",
          "s20", "scc", "memory");
}

// kD: candbits + local/step + 5-iter never-done sim. CS read from the
// Q4-interleaved buffer (same values bitwise). Flags instead of counts.
__global__ void kD_prepare(const float* __restrict__ cons,
                           const float* __restrict__ CSq,
                           const float* __restrict__ init,
                           float* __restrict__ stepv,
                           float* __restrict__ candf,
                           unsigned int* __restrict__ counts) {
    const int idx = blockIdx.x * 256 + threadIdx.x;
    const int b = idx / TT;
    const int t = idx - b * TT;
    __shared__ unsigned sflag[5];
    if (threadIdx.x < 5) sflag[threadIdx.x] = 0u;
    __syncthreads();

    int lo = t - 2; if (lo < 0) lo = 0;
    int hi = t + 3; if (hi > TT) hi = TT;
    int uh = hi - 1;
    float csH = CSq[((uh >> 2) * 16 + b) * 4 + (uh & 3)];
    float csL = 0.f;
    if (lo > 0) {
        int ul = lo - 1;
        csL = CSq[((ul >> 2) * 16 + b) * 4 + (ul & 3)];
    }
    float local = (csH - csL) / (float)(hi - lo);
    float dir = (local > 0.7f) ? -0.1f : ((local < 0.4f) ? 0.1f : 0.0f);
    bool interior = (t >= 1) && (t <= TT - 2);
    float step = interior ? dir : 0.0f;
    float g = (t == 0) ? 0.f : fabsf(cons[idx] - cons[idx - 1]);
    float cand = (g > 0.15f) ? 1.f : 0.f;
    float r = init[idx];
    bool nz[5];
#pragma unroll
    for (int j = 0; j < 5; ++j) {
        float adj = (fmaxf(cand, r) > 0.5f) ? step : 0.0f;
        nz[j] = (adj != 0.0f);
        r = fminf(fmaxf(r + adj, 0.0f), 1.0f);
    }
    stepv[idx] = step; candf[idx] = cand;
    const int lane = threadIdx.x & 63;
#pragma unroll
    for (int j = 0; j < 5; ++j) {
        unsigned long long mb = __ballot(nz[j]);
        if (lane == 0 && mb) atomicOr(&sflag[j], 1u);   // LDS-scope, cheap
    }
    __syncthreads();
    if (threadIdx.x < 5 && sflag[threadIdx.x]) counts[threadIdx.x] = 1u;
}

// K_final: freeze at the first iteration whose adjustment flag is 0.
__global__ void k_final(const float* __restrict__ init,
                        const float* __restrict__ stepv,
                        const float* __restrict__ candf,
                        const unsigned int* __restrict__ counts,
                        float* __restrict__ outp) {
    const int idx = blockIdx.x * 256 + threadIdx.x;
    float r = init[idx];
    float step = stepv[idx];
    float cand = candf[idx];
    unsigned c[5];
#pragma unroll
    for (int j = 0; j < 5; ++j) c[j] = counts[j];
#pragma unroll
    for (int j = 0; j < 5; ++j) {
        if (c[j] == 0u) break;
        float adj = (fmaxf(cand, r) > 0.5f) ? step : 0.0f;
        r = fminf(fmaxf(r + adj, 0.0f), 1.0f);
    }
    outp[idx] = r;
}

extern "C" void kernel_launch(void* const* d_in, const int* in_sizes, int n_in,
                              void* d_out, int out_size, void* d_ws, size_t ws_size,
                              hipStream_t stream) {
    const float* mel  = (const float*)d_in[0];
    const float* spec = (const float*)d_in[1];
    const float* init = (const float*)d_in[2];
    const float* wts  = (const float*)d_in[3];

    float* ws = (float*)d_ws;
    float* ssq   = ws;                 // 192000
    float* dotv  = ws + 192000;        // 192000
    float* cmean = ws + 384000;        // 192000
    float* cons  = ws + 576000;        // 192000 (row-major, for kD)
    float* consq = ws + 768000;        // 192000 (Q4-interleaved)
    float* CSq   = ws + 960000;        // 192000 (Q4-interleaved; absorbs tail prefetch)
    float* stepv = ws + 1152000;       // 192000
    float* candf = ws + 1344000;       // 192000
    float* temporal = ws + 1536000;    // 16
    unsigned int* counts = (unsigned int*)(ws + 1536016); // 8 u32

    dim3 g1((TT + 255) / 256, BB);
    k1_colstats<<<g1, 256, 0, stream>>>(mel, ssq, dotv, cmean, counts);
    kA_temporal<<<BB, 256, 0, stream>>>(cmean, temporal);
    kB_cons<<<BT / 256, 256, 0, stream>>>(ssq, dotv, spec, temporal, wts, cons, consq);
    kC_scan16<<<1, 64, 0, stream>>>(consq, CSq);
    kD_prepare<<<BT / 256, 256, 0, stream>>>(cons, CSq, init, stepv, candf, counts);
    k_final<<<BT / 256, 256, 0, stream>>>(init, stepv, candf, counts, (float*)d_out);
}